// Round 9
// baseline (247.101 us; speedup 1.0000x reference)
//
#include <hip/hip_runtime.h>
#include <hip/hip_fp16.h>

#define HH 1080
#define WW 1920
#define NB 8
#define HWP (HH*WW)                 // 2,073,600
#define NPXs ((size_t)NB*HWP)       // 16,588,800
#define NC4 (WW/4)                  // 480 groups of 4 halves

// LDS pad for K1: +1 word every 32
#define PADI(e) ((e) + ((e) >> 5))

__device__ __forceinline__ int reflH(int y){ int r = y < 0 ? -y : y; return r >= HH ? 2*HH-2-r : r; }

// Bijective XCD-chunked swizzle (handles nwg % 8 != 0; m204 form).
__device__ __forceinline__ int xcd_swz(int p, int nwg){
    int q = nwg >> 3, r = nwg & 7;
    int x = p & 7, idx = p >> 3;
    int start = (x < r) ? x*(q+1) : r*(q+1) + (x - r)*q;
    return start + idx;
}

__device__ __forceinline__ unsigned pkmin(unsigned a, unsigned b){
    unsigned r; asm("v_pk_min_f16 %0, %1, %2" : "=v"(r) : "v"(a), "v"(b)); return r;
}
#define INF2 0x7C007C00u

// ---------------------------------------------------------------- K1: dark channel + horizontal erosion
__global__ __launch_bounds__(256) void k_dark_eh(const float* __restrict__ I,
                                                 __half* __restrict__ dark, __half* __restrict__ eh){
    __shared__ float ds[2048];
    int bid = blockIdx.x;
    int y = bid % HH;
    int b = bid / HH;
    const float* row0 = I + (size_t)b*3*HWP + (size_t)y*WW;
    size_t rb = (size_t)b*HWP + (size_t)y*WW;
    int tid = threadIdx.x;
    if (tid < 240){
        int x0 = tid*8;
        float4 c00 = *(const float4*)(row0 + x0);
        float4 c01 = *(const float4*)(row0 + x0 + 4);
        float4 c10 = *(const float4*)(row0 + HWP + x0);
        float4 c11 = *(const float4*)(row0 + HWP + x0 + 4);
        float4 c20 = *(const float4*)(row0 + 2*HWP + x0);
        float4 c21 = *(const float4*)(row0 + 2*HWP + x0 + 4);
        float m[8];
        m[0]=fminf(fminf(c00.x,c10.x),c20.x); m[1]=fminf(fminf(c00.y,c10.y),c20.y);
        m[2]=fminf(fminf(c00.z,c10.z),c20.z); m[3]=fminf(fminf(c00.w,c10.w),c20.w);
        m[4]=fminf(fminf(c01.x,c11.x),c21.x); m[5]=fminf(fminf(c01.y,c11.y),c21.y);
        m[6]=fminf(fminf(c01.z,c11.z),c21.z); m[7]=fminf(fminf(c01.w,c11.w),c21.w);
        __half2 hd[4];
        #pragma unroll
        for (int l=0;l<4;++l) hd[l] = __floats2half2_rn(m[2*l], m[2*l+1]);
        *(uint4*)(dark + rb + x0) = *(uint4*)hd;
        #pragma unroll
        for (int i=0;i<8;++i) ds[PADI(x0+7+i)] = m[i];
    } else if (tid == 240){
        for (int i=0;i<7;++i) ds[PADI(i)] = 1e30f;
    } else if (tid == 241){
        for (int i=0;i<7;++i) ds[PADI(1927+i)] = 1e30f;
    }
    __syncthreads();
    if (tid >= 240) return;
    int x0 = tid*8;
    float s[22];
    #pragma unroll
    for (int i=0;i<22;++i) s[i] = ds[PADI(x0+i)];
    float t1[21], t2[19], t4[15];
    #pragma unroll
    for (int i=0;i<21;++i) t1[i] = fminf(s[i], s[i+1]);
    #pragma unroll
    for (int i=0;i<19;++i) t2[i] = fminf(t1[i], t1[i+2]);
    #pragma unroll
    for (int i=0;i<15;++i) t4[i] = fminf(t2[i], t2[i+4]);
    __half2 ho[4];
    #pragma unroll
    for (int l=0;l<4;++l){
        float o0 = fminf(t4[2*l],   t4[2*l+7]);
        float o1 = fminf(t4[2*l+1], t4[2*l+8]);
        ho[l] = __floats2half2_rn(o0, o1);
    }
    *(uint4*)(eh + rb + x0) = *(uint4*)ho;
}

// ---------------------------------------------------------------- K2: vertical erosion, Gil-Werman 3-block (EVT=45)
// Window 15 = blocks of 15 rows. out[yb+j] = min(suffix_k[j], prefix_{k+1}[j]).
// While consuming prefix rows of block k+1 we bank them (ns[]) as its suffix
// source for the next iteration: 59 row-loads per 45 outputs (halo 1.31x).
#define EVT 45
__global__ __launch_bounds__(256) void k_erosv(const __half* __restrict__ eh, __half* __restrict__ dim){
    int t = xcd_swz(blockIdx.x, 360)*256 + threadIdx.x;   // 480*8*24 threads, 360 blocks
    int c4 = t % NC4;
    int r  = t / NC4;
    int b  = r & 7;
    int y0 = (r >> 3) * EVT;
    const __half* sp = eh  + (size_t)b*HWP + (size_t)c4*4;
    __half*       dp = dim + (size_t)b*HWP + (size_t)c4*4;
    auto ld = [&](int y)->uint2{
        if ((unsigned)y < HH) return *(const uint2*)(sp + (size_t)y*WW);
        uint2 v; v.x = INF2; v.y = INF2; return v;
    };
    uint2 s[15];
    #pragma unroll
    for (int j=0;j<15;++j) s[j] = ld(y0-7+j);
    #pragma unroll
    for (int j=13;j>=0;--j){ s[j].x = pkmin(s[j].x, s[j+1].x); s[j].y = pkmin(s[j].y, s[j+1].y); }
    #pragma unroll
    for (int k=0;k<3;++k){
        int yb = y0 + 15*k;
        *(uint2*)(dp + (size_t)yb*WW) = s[0];
        uint2 P; P.x = INF2; P.y = INF2;
        uint2 ns[14];
        #pragma unroll
        for (int j=1;j<15;++j){
            uint2 nv = ld(yb+7+j);          // rows [yb+8, yb+21] = next block rows 0..13
            ns[j-1] = nv;
            P.x = pkmin(P.x, nv.x); P.y = pkmin(P.y, nv.y);
            uint2 o; o.x = pkmin(s[j].x, P.x); o.y = pkmin(s[j].y, P.y);
            *(uint2*)(dp + (size_t)(yb+j)*WW) = o;
        }
        if (k < 2){
            s[14] = ld(yb+22);              // last row of next block
            #pragma unroll
            for (int j=13;j>=0;--j){
                s[j].x = pkmin(ns[j].x, s[j+1].x);
                s[j].y = pkmin(ns[j].y, s[j+1].y);
            }
        }
    }
}

// ---------------------------------------------------------------- K3: vertical box-mean of 4 moments -> packed plane
// Packed layout: px p -> halves [4p,4p+4) = {mI, mP, mIp, mII}
#define BT 54
__global__ __launch_bounds__(256) void k_blurv4(const __half* __restrict__ dimp, const __half* __restrict__ darkp,
                                                __half* __restrict__ mp){
    int t = xcd_swz(blockIdx.x, 300)*256 + threadIdx.x;    // 480*8*20 threads, 300 blocks
    int c4 = t % NC4;
    int r  = t / NC4;
    int b  = r & 7;
    int y0 = (r >> 3) * BT;
    size_t base = (size_t)b*HWP + (size_t)c4*4;
    const __half* pd = dimp + base;
    const __half* pk = darkp + base;
    float sI[4], sP[4], sIP[4], sII[4];
    #pragma unroll
    for (int i=0;i<4;++i){ sI[i]=0.f; sP[i]=0.f; sIP[i]=0.f; sII[i]=0.f; }
    auto accA = [&](int yy){
        int yr = reflH(yy);
        uint2 vd = *(const uint2*)(pd + (size_t)yr*WW);
        uint2 vk = *(const uint2*)(pk + (size_t)yr*WW);
        const __half2* hd = (const __half2*)&vd;
        const __half2* hk = (const __half2*)&vk;
        #pragma unroll
        for (int l=0;l<2;++l){
            float2 fd = __half22float2(hd[l]);
            float2 fk = __half22float2(hk[l]);
            sI[2*l]+=fd.x; sI[2*l+1]+=fd.y;
            sP[2*l]+=fk.x; sP[2*l+1]+=fk.y;
            sIP[2*l]+=fd.x*fk.x; sIP[2*l+1]+=fd.y*fk.y;
            sII[2*l]+=fd.x*fd.x; sII[2*l+1]+=fd.y*fd.y;
        }
    };
    auto accS = [&](int yy){
        int yr = reflH(yy);
        uint2 vd = *(const uint2*)(pd + (size_t)yr*WW);
        uint2 vk = *(const uint2*)(pk + (size_t)yr*WW);
        const __half2* hd = (const __half2*)&vd;
        const __half2* hk = (const __half2*)&vk;
        #pragma unroll
        for (int l=0;l<2;++l){
            float2 fd = __half22float2(hd[l]);
            float2 fk = __half22float2(hk[l]);
            sI[2*l]-=fd.x; sI[2*l+1]-=fd.y;
            sP[2*l]-=fk.x; sP[2*l+1]-=fk.y;
            sIP[2*l]-=fd.x*fk.x; sIP[2*l+1]-=fd.y*fk.y;
            sII[2*l]-=fd.x*fd.x; sII[2*l+1]-=fd.y*fd.y;
        }
    };
    const float inv = 1.0f/60.0f;
    for (int k=-29;k<=30;++k) accA(y0+k);
    auto emit = [&](int y){
        size_t off = (base + (size_t)y*WW) * 4;   // half units in packed plane
        __half2 h[4];
        h[0]=__floats2half2_rn(sI[0]*inv,  sP[0]*inv);
        h[1]=__floats2half2_rn(sIP[0]*inv, sII[0]*inv);
        h[2]=__floats2half2_rn(sI[1]*inv,  sP[1]*inv);
        h[3]=__floats2half2_rn(sIP[1]*inv, sII[1]*inv);
        *(uint4*)(mp+off) = *(uint4*)h;
        h[0]=__floats2half2_rn(sI[2]*inv,  sP[2]*inv);
        h[1]=__floats2half2_rn(sIP[2]*inv, sII[2]*inv);
        h[2]=__floats2half2_rn(sI[3]*inv,  sP[3]*inv);
        h[3]=__floats2half2_rn(sIP[3]*inv, sII[3]*inv);
        *(uint4*)(mp+off+8) = *(uint4*)h;
    };
    emit(y0);
    for (int y=y0+1; y<y0+BT; ++y){
        accA(y+30);
        accS(y-30);
        emit(y);
    }
}

// ---------------------------------------------------------------- K4: H-blur(moments) + a,b + H-blur(a,b) via prefix scans
__global__ __launch_bounds__(256) void k_hab(const __half* __restrict__ mp, __half* __restrict__ abp){
    __shared__ float4 PA[4][256];
    __shared__ float4 PB[4][256];
    __shared__ float4 QA[2][264];
    __shared__ float4 QB[2][264];
    __shared__ float wt[4][4];
    __shared__ float wt2[2][4];

    int bid = blockIdx.x;
    int y = bid % HH;
    int b = bid / HH;
    size_t rb = (size_t)b*HWP + (size_t)y*WW;
    int tid = threadIdx.x;
    int lane = tid & 63;
    int wv = tid >> 6;

    const __half* mrow = mp + rb*4;

    // ---- scan-input loads
    float xv[4][8];
    int u = tid;
    if (u >= 4 && u <= 243){
        int x0 = 8*(u-4);
        const __half* pbase = mrow + (size_t)4*x0;
        uint4 vv[4];
        vv[0] = *(const uint4*)(pbase);
        vv[1] = *(const uint4*)(pbase + 8);
        vv[2] = *(const uint4*)(pbase + 16);
        vv[3] = *(const uint4*)(pbase + 24);
        #pragma unroll
        for (int i=0;i<8;++i){
            const __half2* hh = (const __half2*)&vv[i>>1];
            float2 fa = __half22float2(hh[(i&1)*2]);
            float2 fb = __half22float2(hh[(i&1)*2+1]);
            xv[0][i]=fa.x; xv[1][i]=fa.y; xv[2][i]=fb.x; xv[3][i]=fb.y;
        }
    } else {
        #pragma unroll
        for (int i=0;i<8;++i){
            int s = 8*u + i;
            if (s >= 3 && s <= 1981){
                int j = s - 3;
                int x = j - 29;
                if (x < 0) x = -x;
                else if (x > 1919) x = 3838 - x;
                uint2 u2 = *(const uint2*)(mrow + (size_t)4*x);
                const __half2* hh = (const __half2*)&u2;
                float2 fa = __half22float2(hh[0]);
                float2 fb = __half22float2(hh[1]);
                xv[0][i]=fa.x; xv[1][i]=fa.y; xv[2][i]=fb.x; xv[3][i]=fb.y;
            } else {
                xv[0][i]=0.f; xv[1][i]=0.f; xv[2][i]=0.f; xv[3][i]=0.f;
            }
        }
    }

    // ---- local prefix + wave scan
    float ebase[4];
    #pragma unroll
    for (int p=0;p<4;++p){
        #pragma unroll
        for (int i=1;i<8;++i) xv[p][i] += xv[p][i-1];
        float v = xv[p][7];
        #pragma unroll
        for (int d=1; d<64; d<<=1){
            float tmp = __shfl_up(v, d);
            if (lane >= d) v += tmp;
        }
        ebase[p] = v - xv[p][7];
        if (lane == 63) wt[p][wv] = v;
    }
    __syncthreads();
    #pragma unroll
    for (int p=0;p<4;++p){
        float bb = ebase[p];
        if (wv > 0) bb += wt[p][0];
        if (wv > 1) bb += wt[p][1];
        if (wv > 2) bb += wt[p][2];
        #pragma unroll
        for (int i=0;i<8;++i) xv[p][i] += bb;   // xv[p][i] = Pi[8u+i]
        if (u > 0) *((float2*)&PB[p][u-1] + 1) = make_float2(xv[p][0], xv[p][1]);
        PA[p][u] = make_float4(xv[p][2], xv[p][3], xv[p][4], xv[p][5]);
        *((float2*)&PB[p][u]) = make_float2(xv[p][6], xv[p][7]);
    }
    __syncthreads();

    // ---- phase 3a: window means + a,b
    float Aa[8], Bb[8];
    int t = tid;
    if (t < 240){
        const float inv = 1.0f/60.0f;
        float mm[4][8];
        #pragma unroll
        for (int p=0;p<4;++p){
            float4 loa = PA[p][t];
            float4 lob = PB[p][t];
            float4 hib = PB[p][t+7];
            float4 hia = PA[p][t+8];
            mm[p][0]=(hib.x-loa.x)*inv; mm[p][1]=(hib.y-loa.y)*inv;
            mm[p][2]=(hib.z-loa.z)*inv; mm[p][3]=(hib.w-loa.w)*inv;
            mm[p][4]=(hia.x-lob.x)*inv; mm[p][5]=(hia.y-lob.y)*inv;
            mm[p][6]=(hia.z-lob.z)*inv; mm[p][7]=(hia.w-lob.w)*inv;
        }
        #pragma unroll
        for (int i=0;i<8;++i){
            float mI=mm[0][i], mP=mm[1][i], mIp=mm[2][i], mII=mm[3][i];
            float cov = mIp - mI*mP;
            float var = mII - mI*mI;
            float a = cov / (var + 1e-4f);
            Aa[i] = a;
            Bb[i] = mP - a*mI;
        }
    } else {
        #pragma unroll
        for (int i=0;i<8;++i){ Aa[i]=0.f; Bb[i]=0.f; }
    }

    // ---- scan2 over a and b (x-grid, 1920 values in threads 0..239)
    float eA, eB;
    {
        #pragma unroll
        for (int i=1;i<8;++i) Aa[i] += Aa[i-1];
        float v = Aa[7];
        #pragma unroll
        for (int d=1; d<64; d<<=1){
            float tmp = __shfl_up(v, d);
            if (lane >= d) v += tmp;
        }
        eA = v - Aa[7];
        if (lane==63) wt2[0][wv] = v;
    }
    {
        #pragma unroll
        for (int i=1;i<8;++i) Bb[i] += Bb[i-1];
        float v = Bb[7];
        #pragma unroll
        for (int d=1; d<64; d<<=1){
            float tmp = __shfl_up(v, d);
            if (lane >= d) v += tmp;
        }
        eB = v - Bb[7];
        if (lane==63) wt2[1][wv] = v;
    }
    __syncthreads();
    {
        float bb = eA;
        if (wv>0) bb += wt2[0][0];
        if (wv>1) bb += wt2[0][1];
        if (wv>2) bb += wt2[0][2];
        #pragma unroll
        for (int i=0;i<8;++i) Aa[i] += bb;      // Aa[i] = Pr_a[8t+i]
        bb = eB;
        if (wv>0) bb += wt2[1][0];
        if (wv>1) bb += wt2[1][1];
        if (wv>2) bb += wt2[1][2];
        #pragma unroll
        for (int i=0;i<8;++i) Bb[i] += bb;
    }
    // PrS writes: cells z=8t+30..8t+37 hold Pr[8t..8t+7]
    *((float2*)&QB[0][t+3] + 1) = make_float2(Aa[0], Aa[1]);
    QA[0][t+4] = make_float4(Aa[2], Aa[3], Aa[4], Aa[5]);
    *((float2*)&QB[0][t+4]) = make_float2(Aa[6], Aa[7]);
    *((float2*)&QB[1][t+3] + 1) = make_float2(Bb[0], Bb[1]);
    QA[1][t+4] = make_float4(Bb[2], Bb[3], Bb[4], Bb[5]);
    *((float2*)&QB[1][t+4]) = make_float2(Bb[6], Bb[7]);
    if (tid >= 248){
        int k = tid - 248;
        float4 z4 = make_float4(0.f,0.f,0.f,0.f);
        if (k < 4){ QA[0][k] = z4; QA[1][k] = z4; }
        else if (k < 7){ QB[0][k-4] = z4; QB[1][k-4] = z4; }
        else { *((float2*)&QB[0][3]) = make_float2(0.f,0.f);
               *((float2*)&QB[1][3]) = make_float2(0.f,0.f); }
    }
    __syncthreads();
    if (t >= 240) return;

    // ---- phase 3c: second blur outputs
    int x0 = 8*t;
    float4 lA0 = QA[0][t];   float4 lA1 = QB[0][t];
    float4 hA0 = QB[0][t+7]; float4 hA1 = QA[0][t+8];
    float4 lB0 = QA[1][t];   float4 lB1 = QB[1][t];
    float4 hB0 = QB[1][t+7]; float4 hB1 = QA[1][t+8];
    float sA[8], sB[8];
    sA[0]=hA0.x-lA0.x; sA[1]=hA0.y-lA0.y; sA[2]=hA0.z-lA0.z; sA[3]=hA0.w-lA0.w;
    sA[4]=hA1.x-lA1.x; sA[5]=hA1.y-lA1.y; sA[6]=hA1.z-lA1.z; sA[7]=hA1.w-lA1.w;
    sB[0]=hB0.x-lB0.x; sB[1]=hB0.y-lB0.y; sB[2]=hB0.z-lB0.z; sB[3]=hB0.w-lB0.w;
    sB[4]=hB1.x-lB1.x; sB[5]=hB1.y-lB1.y; sB[6]=hB1.z-lB1.z; sB[7]=hB1.w-lB1.w;

    auto prRead = [&](int pl, int v)->float{
        int z = v + 30;
        int c = z >> 2;
        float4 f = (c & 1) ? QB[pl][c>>1] : QA[pl][c>>1];
        int w = z & 3;
        return (w==0)?f.x:((w==1)?f.y:((w==2)?f.z:f.w));
    };
    if (x0 < 29){
        #pragma unroll
        for (int i=0;i<8;++i){
            int x = x0 + i;
            if (x < 29){
                sA[i] += prRead(0, 29-x) - prRead(0, 0);
                sB[i] += prRead(1, 29-x) - prRead(1, 0);
            }
        }
    }
    if (x0 + 7 > 1889){
        #pragma unroll
        for (int i=0;i<8;++i){
            int x = x0 + i;
            if (x > 1889){
                sA[i] += prRead(0, 1918) - prRead(0, 3807-x);
                sB[i] += prRead(1, 1918) - prRead(1, 3807-x);
            }
        }
    }
    const float inv = 1.0f/60.0f;
    __half2 hab[8];
    #pragma unroll
    for (int i=0;i<8;++i) hab[i] = __floats2half2_rn(sA[i]*inv, sB[i]*inv);
    size_t ro = (rb + (size_t)x0) * 2;
    *(uint4*)(abp + ro)     = *(uint4*)&hab[0];
    *(uint4*)(abp + ro + 8) = *(uint4*)&hab[4];
}

// ---------------------------------------------------------------- K5: vertical box-mean of packed ab + q
__global__ __launch_bounds__(256) void k_final(const __half* __restrict__ abp,
                                               const __half* __restrict__ dimp, float* __restrict__ q){
    int t = xcd_swz(blockIdx.x, 300)*256 + threadIdx.x;    // 480*8*20 threads, 300 blocks
    int c4 = t % NC4;
    int r  = t / NC4;
    int b  = r & 7;
    int y0 = (r >> 3) * BT;
    size_t base = (size_t)b*HWP + (size_t)c4*4;
    const __half* pab = abp + base*2;
    const __half* pd  = dimp + base;
    float* pq = q + base;
    float sa[4], sb[4];
    #pragma unroll
    for (int i=0;i<4;++i){ sa[i]=0.f; sb[i]=0.f; }
    auto accA = [&](int yy){
        int yr = reflH(yy);
        uint4 v = *(const uint4*)(pab + (size_t)yr*WW*2);
        const __half2* h = (const __half2*)&v;
        #pragma unroll
        for (int l=0;l<4;++l){
            float2 f = __half22float2(h[l]);
            sa[l]+=f.x; sb[l]+=f.y;
        }
    };
    auto accS = [&](int yy){
        int yr = reflH(yy);
        uint4 v = *(const uint4*)(pab + (size_t)yr*WW*2);
        const __half2* h = (const __half2*)&v;
        #pragma unroll
        for (int l=0;l<4;++l){
            float2 f = __half22float2(h[l]);
            sa[l]-=f.x; sb[l]-=f.y;
        }
    };
    const float inv = 1.0f/60.0f;
    for (int k=-29;k<=30;++k) accA(y0+k);
    auto emit = [&](int y){
        uint2 vd = *(const uint2*)(pd + (size_t)y*WW);
        const __half2* hd = (const __half2*)&vd;
        float2 f0 = __half22float2(hd[0]);
        float2 f1 = __half22float2(hd[1]);
        float4 o;
        o.x = (sa[0]*inv)*f0.x + sb[0]*inv;
        o.y = (sa[1]*inv)*f0.y + sb[1]*inv;
        o.z = (sa[2]*inv)*f1.x + sb[2]*inv;
        o.w = (sa[3]*inv)*f1.y + sb[3]*inv;
        *(float4*)(pq + (size_t)y*WW) = o;
    };
    emit(y0);
    for (int y=y0+1; y<y0+BT; ++y){
        accA(y+30);
        accS(y-30);
        emit(y);
    }
}

// ---------------------------------------------------------------- launch
extern "C" void kernel_launch(void* const* d_in, const int* in_sizes, int n_in,
                              void* d_out, int out_size, void* d_ws, size_t ws_size,
                              hipStream_t stream){
    const float* I = (const float*)d_in[0];
    float* qout = (float*)d_out;
    __half* ws = (__half*)d_ws;

    __half* p_dark = ws;                 // [0, NPXs)
    __half* p_eh   = ws + NPXs;          // [NPXs, 2N)
    __half* p_dim  = ws + 2*NPXs;        // [2N, 3N)
    __half* p_mp   = ws + 3*NPXs;        // [3N, 7N) packed 4 moments
    __half* p_ab   = ws;                 // aliases dark+eh (both dead before k_hab)

    k_dark_eh<<<NB*HH, 256, 0, stream>>>(I, p_dark, p_eh);
    k_erosv  <<<360,   256, 0, stream>>>(p_eh, p_dim);
    k_blurv4 <<<300,   256, 0, stream>>>(p_dim, p_dark, p_mp);
    k_hab    <<<NB*HH, 256, 0, stream>>>(p_mp, p_ab);
    k_final  <<<300,   256, 0, stream>>>(p_ab, p_dim, qout);
}

// Round 10
// 243.657 us; speedup vs baseline: 1.0141x; 1.0141x over previous
//
#include <hip/hip_runtime.h>
#include <hip/hip_fp16.h>

#define HH 1080
#define WW 1920
#define NB 8
#define HWP (HH*WW)                 // 2,073,600
#define NPXs ((size_t)NB*HWP)       // 16,588,800
#define NC4 (WW/4)                  // 480 groups of 4 halves
#define NC8 (WW/8)                  // 240 groups of 8 halves

// LDS pad for K1: +1 word every 32
#define PADI(e) ((e) + ((e) >> 5))

__device__ __forceinline__ int reflH(int y){ int r = y < 0 ? -y : y; return r >= HH ? 2*HH-2-r : r; }

// Bijective XCD-chunked swizzle (handles nwg % 8 != 0; m204 form).
__device__ __forceinline__ int xcd_swz(int p, int nwg){
    int q = nwg >> 3, r = nwg & 7;
    int x = p & 7, idx = p >> 3;
    int start = (x < r) ? x*(q+1) : r*(q+1) + (x - r)*q;
    return start + idx;
}

__device__ __forceinline__ unsigned pkmin(unsigned a, unsigned b){
    unsigned r; asm("v_pk_min_f16 %0, %1, %2" : "=v"(r) : "v"(a), "v"(b)); return r;
}
#define INF2 0x7C007C00u

// ---------------------------------------------------------------- K1: dark channel + horizontal erosion
__global__ __launch_bounds__(256) void k_dark_eh(const float* __restrict__ I,
                                                 __half* __restrict__ dark, __half* __restrict__ eh){
    __shared__ float ds[2048];
    int bid = blockIdx.x;
    int y = bid % HH;
    int b = bid / HH;
    const float* row0 = I + (size_t)b*3*HWP + (size_t)y*WW;
    size_t rb = (size_t)b*HWP + (size_t)y*WW;
    int tid = threadIdx.x;
    if (tid < 240){
        int x0 = tid*8;
        float4 c00 = *(const float4*)(row0 + x0);
        float4 c01 = *(const float4*)(row0 + x0 + 4);
        float4 c10 = *(const float4*)(row0 + HWP + x0);
        float4 c11 = *(const float4*)(row0 + HWP + x0 + 4);
        float4 c20 = *(const float4*)(row0 + 2*HWP + x0);
        float4 c21 = *(const float4*)(row0 + 2*HWP + x0 + 4);
        float m[8];
        m[0]=fminf(fminf(c00.x,c10.x),c20.x); m[1]=fminf(fminf(c00.y,c10.y),c20.y);
        m[2]=fminf(fminf(c00.z,c10.z),c20.z); m[3]=fminf(fminf(c00.w,c10.w),c20.w);
        m[4]=fminf(fminf(c01.x,c11.x),c21.x); m[5]=fminf(fminf(c01.y,c11.y),c21.y);
        m[6]=fminf(fminf(c01.z,c11.z),c21.z); m[7]=fminf(fminf(c01.w,c11.w),c21.w);
        __half2 hd[4];
        #pragma unroll
        for (int l=0;l<4;++l) hd[l] = __floats2half2_rn(m[2*l], m[2*l+1]);
        *(uint4*)(dark + rb + x0) = *(uint4*)hd;
        #pragma unroll
        for (int i=0;i<8;++i) ds[PADI(x0+7+i)] = m[i];
    } else if (tid == 240){
        for (int i=0;i<7;++i) ds[PADI(i)] = 1e30f;
    } else if (tid == 241){
        for (int i=0;i<7;++i) ds[PADI(1927+i)] = 1e30f;
    }
    __syncthreads();
    if (tid >= 240) return;
    int x0 = tid*8;
    float s[22];
    #pragma unroll
    for (int i=0;i<22;++i) s[i] = ds[PADI(x0+i)];
    float t1[21], t2[19], t4[15];
    #pragma unroll
    for (int i=0;i<21;++i) t1[i] = fminf(s[i], s[i+1]);
    #pragma unroll
    for (int i=0;i<19;++i) t2[i] = fminf(t1[i], t1[i+2]);
    #pragma unroll
    for (int i=0;i<15;++i) t4[i] = fminf(t2[i], t2[i+4]);
    __half2 ho[4];
    #pragma unroll
    for (int l=0;l<4;++l){
        float o0 = fminf(t4[2*l],   t4[2*l+7]);
        float o1 = fminf(t4[2*l+1], t4[2*l+8]);
        ho[l] = __floats2half2_rn(o0, o1);
    }
    *(uint4*)(eh + rb + x0) = *(uint4*)ho;
}

// ---------------------------------------------------------------- K2: vertical erosion (window 15), uint4 width
__global__ __launch_bounds__(256) void k_erosv(const __half* __restrict__ eh, __half* __restrict__ dim){
    int t = xcd_swz(blockIdx.x, 540)*256 + threadIdx.x;   // 240*8*72 threads, 540 blocks
    int c8 = t % NC8;
    int r  = t / NC8;
    int b  = r & 7;
    int y0 = (r >> 3) * 15;
    const __half* sp = eh  + (size_t)b*HWP + (size_t)c8*8;
    __half*       dp = dim + (size_t)b*HWP + (size_t)c8*8;
    uint4 s[15];
    #pragma unroll
    for (int j=0;j<15;++j){
        int y = y0 - 7 + j;
        if ((unsigned)y < HH) s[j] = *(const uint4*)(sp + (size_t)y*WW);
        else s[j] = make_uint4(INF2,INF2,INF2,INF2);
    }
    #pragma unroll
    for (int j=13;j>=0;--j){
        s[j].x = pkmin(s[j].x, s[j+1].x); s[j].y = pkmin(s[j].y, s[j+1].y);
        s[j].z = pkmin(s[j].z, s[j+1].z); s[j].w = pkmin(s[j].w, s[j+1].w);
    }
    *(uint4*)(dp + (size_t)y0*WW) = s[0];
    uint4 P = make_uint4(INF2,INF2,INF2,INF2);
    #pragma unroll
    for (int j=1;j<15;++j){
        int y = y0 + 7 + j;
        uint4 nv;
        if ((unsigned)y < HH) nv = *(const uint4*)(sp + (size_t)y*WW);
        else nv = make_uint4(INF2,INF2,INF2,INF2);
        P.x = pkmin(P.x, nv.x); P.y = pkmin(P.y, nv.y);
        P.z = pkmin(P.z, nv.z); P.w = pkmin(P.w, nv.w);
        uint4 o;
        o.x = pkmin(s[j].x, P.x); o.y = pkmin(s[j].y, P.y);
        o.z = pkmin(s[j].z, P.z); o.w = pkmin(s[j].w, P.w);
        *(uint4*)(dp + (size_t)(y0+j)*WW) = o;
    }
}

// ---------------------------------------------------------------- K3: vertical box-mean of 4 moments -> packed plane
// Packed layout: px p -> halves [4p,4p+4) = {mI, mP, mIp, mII}
#define BT 54
__global__ __launch_bounds__(256) void k_blurv4(const __half* __restrict__ dimp, const __half* __restrict__ darkp,
                                                __half* __restrict__ mp){
    int t = xcd_swz(blockIdx.x, 300)*256 + threadIdx.x;    // 480*8*20 threads, 300 blocks
    int c4 = t % NC4;
    int r  = t / NC4;
    int b  = r & 7;
    int y0 = (r >> 3) * BT;
    size_t base = (size_t)b*HWP + (size_t)c4*4;
    const __half* pd = dimp + base;
    const __half* pk = darkp + base;
    float sI[4], sP[4], sIP[4], sII[4];
    #pragma unroll
    for (int i=0;i<4;++i){ sI[i]=0.f; sP[i]=0.f; sIP[i]=0.f; sII[i]=0.f; }
    auto accA = [&](int yy){
        int yr = reflH(yy);
        uint2 vd = *(const uint2*)(pd + (size_t)yr*WW);
        uint2 vk = *(const uint2*)(pk + (size_t)yr*WW);
        const __half2* hd = (const __half2*)&vd;
        const __half2* hk = (const __half2*)&vk;
        #pragma unroll
        for (int l=0;l<2;++l){
            float2 fd = __half22float2(hd[l]);
            float2 fk = __half22float2(hk[l]);
            sI[2*l]+=fd.x; sI[2*l+1]+=fd.y;
            sP[2*l]+=fk.x; sP[2*l+1]+=fk.y;
            sIP[2*l]+=fd.x*fk.x; sIP[2*l+1]+=fd.y*fk.y;
            sII[2*l]+=fd.x*fd.x; sII[2*l+1]+=fd.y*fd.y;
        }
    };
    auto accS = [&](int yy){
        int yr = reflH(yy);
        uint2 vd = *(const uint2*)(pd + (size_t)yr*WW);
        uint2 vk = *(const uint2*)(pk + (size_t)yr*WW);
        const __half2* hd = (const __half2*)&vd;
        const __half2* hk = (const __half2*)&vk;
        #pragma unroll
        for (int l=0;l<2;++l){
            float2 fd = __half22float2(hd[l]);
            float2 fk = __half22float2(hk[l]);
            sI[2*l]-=fd.x; sI[2*l+1]-=fd.y;
            sP[2*l]-=fk.x; sP[2*l+1]-=fk.y;
            sIP[2*l]-=fd.x*fk.x; sIP[2*l+1]-=fd.y*fk.y;
            sII[2*l]-=fd.x*fd.x; sII[2*l+1]-=fd.y*fd.y;
        }
    };
    const float inv = 1.0f/60.0f;
    for (int k=-29;k<=30;++k) accA(y0+k);
    auto emit = [&](int y){
        size_t off = (base + (size_t)y*WW) * 4;   // half units in packed plane
        __half2 h[4];
        h[0]=__floats2half2_rn(sI[0]*inv,  sP[0]*inv);
        h[1]=__floats2half2_rn(sIP[0]*inv, sII[0]*inv);
        h[2]=__floats2half2_rn(sI[1]*inv,  sP[1]*inv);
        h[3]=__floats2half2_rn(sIP[1]*inv, sII[1]*inv);
        *(uint4*)(mp+off) = *(uint4*)h;
        h[0]=__floats2half2_rn(sI[2]*inv,  sP[2]*inv);
        h[1]=__floats2half2_rn(sIP[2]*inv, sII[2]*inv);
        h[2]=__floats2half2_rn(sI[3]*inv,  sP[3]*inv);
        h[3]=__floats2half2_rn(sIP[3]*inv, sII[3]*inv);
        *(uint4*)(mp+off+8) = *(uint4*)h;
    };
    emit(y0);
    for (int y=y0+1; y<y0+BT; ++y){
        accA(y+30);
        accS(y-30);
        emit(y);
    }
}

// ---------------------------------------------------------------- K4: H-blur(moments) + a,b + H-blur(a,b) via prefix scans
__global__ __launch_bounds__(256) void k_hab(const __half* __restrict__ mp, __half* __restrict__ abp){
    __shared__ float4 PA[4][256];
    __shared__ float4 PB[4][256];
    __shared__ float4 QA[2][264];
    __shared__ float4 QB[2][264];
    __shared__ float wt[4][4];
    __shared__ float wt2[2][4];

    int bid = blockIdx.x;
    int y = bid % HH;
    int b = bid / HH;
    size_t rb = (size_t)b*HWP + (size_t)y*WW;
    int tid = threadIdx.x;
    int lane = tid & 63;
    int wv = tid >> 6;

    const __half* mrow = mp + rb*4;

    // ---- scan-input loads
    float xv[4][8];
    int u = tid;
    if (u >= 4 && u <= 243){
        int x0 = 8*(u-4);
        const __half* pbase = mrow + (size_t)4*x0;
        uint4 vv[4];
        vv[0] = *(const uint4*)(pbase);
        vv[1] = *(const uint4*)(pbase + 8);
        vv[2] = *(const uint4*)(pbase + 16);
        vv[3] = *(const uint4*)(pbase + 24);
        #pragma unroll
        for (int i=0;i<8;++i){
            const __half2* hh = (const __half2*)&vv[i>>1];
            float2 fa = __half22float2(hh[(i&1)*2]);
            float2 fb = __half22float2(hh[(i&1)*2+1]);
            xv[0][i]=fa.x; xv[1][i]=fa.y; xv[2][i]=fb.x; xv[3][i]=fb.y;
        }
    } else {
        #pragma unroll
        for (int i=0;i<8;++i){
            int s = 8*u + i;
            if (s >= 3 && s <= 1981){
                int j = s - 3;
                int x = j - 29;
                if (x < 0) x = -x;
                else if (x > 1919) x = 3838 - x;
                uint2 u2 = *(const uint2*)(mrow + (size_t)4*x);
                const __half2* hh = (const __half2*)&u2;
                float2 fa = __half22float2(hh[0]);
                float2 fb = __half22float2(hh[1]);
                xv[0][i]=fa.x; xv[1][i]=fa.y; xv[2][i]=fb.x; xv[3][i]=fb.y;
            } else {
                xv[0][i]=0.f; xv[1][i]=0.f; xv[2][i]=0.f; xv[3][i]=0.f;
            }
        }
    }

    // ---- local prefix + wave scan
    float ebase[4];
    #pragma unroll
    for (int p=0;p<4;++p){
        #pragma unroll
        for (int i=1;i<8;++i) xv[p][i] += xv[p][i-1];
        float v = xv[p][7];
        #pragma unroll
        for (int d=1; d<64; d<<=1){
            float tmp = __shfl_up(v, d);
            if (lane >= d) v += tmp;
        }
        ebase[p] = v - xv[p][7];
        if (lane == 63) wt[p][wv] = v;
    }
    __syncthreads();
    #pragma unroll
    for (int p=0;p<4;++p){
        float bb = ebase[p];
        if (wv > 0) bb += wt[p][0];
        if (wv > 1) bb += wt[p][1];
        if (wv > 2) bb += wt[p][2];
        #pragma unroll
        for (int i=0;i<8;++i) xv[p][i] += bb;   // xv[p][i] = Pi[8u+i]
        if (u > 0) *((float2*)&PB[p][u-1] + 1) = make_float2(xv[p][0], xv[p][1]);
        PA[p][u] = make_float4(xv[p][2], xv[p][3], xv[p][4], xv[p][5]);
        *((float2*)&PB[p][u]) = make_float2(xv[p][6], xv[p][7]);
    }
    __syncthreads();

    // ---- phase 3a: window means + a,b
    float Aa[8], Bb[8];
    int t = tid;
    if (t < 240){
        const float inv = 1.0f/60.0f;
        float mm[4][8];
        #pragma unroll
        for (int p=0;p<4;++p){
            float4 loa = PA[p][t];
            float4 lob = PB[p][t];
            float4 hib = PB[p][t+7];
            float4 hia = PA[p][t+8];
            mm[p][0]=(hib.x-loa.x)*inv; mm[p][1]=(hib.y-loa.y)*inv;
            mm[p][2]=(hib.z-loa.z)*inv; mm[p][3]=(hib.w-loa.w)*inv;
            mm[p][4]=(hia.x-lob.x)*inv; mm[p][5]=(hia.y-lob.y)*inv;
            mm[p][6]=(hia.z-lob.z)*inv; mm[p][7]=(hia.w-lob.w)*inv;
        }
        #pragma unroll
        for (int i=0;i<8;++i){
            float mI=mm[0][i], mP=mm[1][i], mIp=mm[2][i], mII=mm[3][i];
            float cov = mIp - mI*mP;
            float var = mII - mI*mI;
            float a = cov / (var + 1e-4f);
            Aa[i] = a;
            Bb[i] = mP - a*mI;
        }
    } else {
        #pragma unroll
        for (int i=0;i<8;++i){ Aa[i]=0.f; Bb[i]=0.f; }
    }

    // ---- scan2 over a and b (x-grid, 1920 values in threads 0..239)
    float eA, eB;
    {
        #pragma unroll
        for (int i=1;i<8;++i) Aa[i] += Aa[i-1];
        float v = Aa[7];
        #pragma unroll
        for (int d=1; d<64; d<<=1){
            float tmp = __shfl_up(v, d);
            if (lane >= d) v += tmp;
        }
        eA = v - Aa[7];
        if (lane==63) wt2[0][wv] = v;
    }
    {
        #pragma unroll
        for (int i=1;i<8;++i) Bb[i] += Bb[i-1];
        float v = Bb[7];
        #pragma unroll
        for (int d=1; d<64; d<<=1){
            float tmp = __shfl_up(v, d);
            if (lane >= d) v += tmp;
        }
        eB = v - Bb[7];
        if (lane==63) wt2[1][wv] = v;
    }
    __syncthreads();
    {
        float bb = eA;
        if (wv>0) bb += wt2[0][0];
        if (wv>1) bb += wt2[0][1];
        if (wv>2) bb += wt2[0][2];
        #pragma unroll
        for (int i=0;i<8;++i) Aa[i] += bb;      // Aa[i] = Pr_a[8t+i]
        bb = eB;
        if (wv>0) bb += wt2[1][0];
        if (wv>1) bb += wt2[1][1];
        if (wv>2) bb += wt2[1][2];
        #pragma unroll
        for (int i=0;i<8;++i) Bb[i] += bb;
    }
    // PrS writes: cells z=8t+30..8t+37 hold Pr[8t..8t+7]
    *((float2*)&QB[0][t+3] + 1) = make_float2(Aa[0], Aa[1]);
    QA[0][t+4] = make_float4(Aa[2], Aa[3], Aa[4], Aa[5]);
    *((float2*)&QB[0][t+4]) = make_float2(Aa[6], Aa[7]);
    *((float2*)&QB[1][t+3] + 1) = make_float2(Bb[0], Bb[1]);
    QA[1][t+4] = make_float4(Bb[2], Bb[3], Bb[4], Bb[5]);
    *((float2*)&QB[1][t+4]) = make_float2(Bb[6], Bb[7]);
    if (tid >= 248){
        int k = tid - 248;
        float4 z4 = make_float4(0.f,0.f,0.f,0.f);
        if (k < 4){ QA[0][k] = z4; QA[1][k] = z4; }
        else if (k < 7){ QB[0][k-4] = z4; QB[1][k-4] = z4; }
        else { *((float2*)&QB[0][3]) = make_float2(0.f,0.f);
               *((float2*)&QB[1][3]) = make_float2(0.f,0.f); }
    }
    __syncthreads();
    if (t >= 240) return;

    // ---- phase 3c: second blur outputs
    int x0 = 8*t;
    float4 lA0 = QA[0][t];   float4 lA1 = QB[0][t];
    float4 hA0 = QB[0][t+7]; float4 hA1 = QA[0][t+8];
    float4 lB0 = QA[1][t];   float4 lB1 = QB[1][t];
    float4 hB0 = QB[1][t+7]; float4 hB1 = QA[1][t+8];
    float sA[8], sB[8];
    sA[0]=hA0.x-lA0.x; sA[1]=hA0.y-lA0.y; sA[2]=hA0.z-lA0.z; sA[3]=hA0.w-lA0.w;
    sA[4]=hA1.x-lA1.x; sA[5]=hA1.y-lA1.y; sA[6]=hA1.z-lA1.z; sA[7]=hA1.w-lA1.w;
    sB[0]=hB0.x-lB0.x; sB[1]=hB0.y-lB0.y; sB[2]=hB0.z-lB0.z; sB[3]=hB0.w-lB0.w;
    sB[4]=hB1.x-lB1.x; sB[5]=hB1.y-lB1.y; sB[6]=hB1.z-lB1.z; sB[7]=hB1.w-lB1.w;

    auto prRead = [&](int pl, int v)->float{
        int z = v + 30;
        int c = z >> 2;
        float4 f = (c & 1) ? QB[pl][c>>1] : QA[pl][c>>1];
        int w = z & 3;
        return (w==0)?f.x:((w==1)?f.y:((w==2)?f.z:f.w));
    };
    if (x0 < 29){
        #pragma unroll
        for (int i=0;i<8;++i){
            int x = x0 + i;
            if (x < 29){
                sA[i] += prRead(0, 29-x) - prRead(0, 0);
                sB[i] += prRead(1, 29-x) - prRead(1, 0);
            }
        }
    }
    if (x0 + 7 > 1889){
        #pragma unroll
        for (int i=0;i<8;++i){
            int x = x0 + i;
            if (x > 1889){
                sA[i] += prRead(0, 1918) - prRead(0, 3807-x);
                sB[i] += prRead(1, 1918) - prRead(1, 3807-x);
            }
        }
    }
    const float inv = 1.0f/60.0f;
    __half2 hab[8];
    #pragma unroll
    for (int i=0;i<8;++i) hab[i] = __floats2half2_rn(sA[i]*inv, sB[i]*inv);
    size_t ro = (rb + (size_t)x0) * 2;
    *(uint4*)(abp + ro)     = *(uint4*)&hab[0];
    *(uint4*)(abp + ro + 8) = *(uint4*)&hab[4];
}

// ---------------------------------------------------------------- K5: vertical box-mean of packed ab + q
__global__ __launch_bounds__(256) void k_final(const __half* __restrict__ abp,
                                               const __half* __restrict__ dimp, float* __restrict__ q){
    int t = xcd_swz(blockIdx.x, 300)*256 + threadIdx.x;    // 480*8*20 threads, 300 blocks
    int c4 = t % NC4;
    int r  = t / NC4;
    int b  = r & 7;
    int y0 = (r >> 3) * BT;
    size_t base = (size_t)b*HWP + (size_t)c4*4;
    const __half* pab = abp + base*2;
    const __half* pd  = dimp + base;
    float* pq = q + base;
    float sa[4], sb[4];
    #pragma unroll
    for (int i=0;i<4;++i){ sa[i]=0.f; sb[i]=0.f; }
    auto accA = [&](int yy){
        int yr = reflH(yy);
        uint4 v = *(const uint4*)(pab + (size_t)yr*WW*2);
        const __half2* h = (const __half2*)&v;
        #pragma unroll
        for (int l=0;l<4;++l){
            float2 f = __half22float2(h[l]);
            sa[l]+=f.x; sb[l]+=f.y;
        }
    };
    auto accS = [&](int yy){
        int yr = reflH(yy);
        uint4 v = *(const uint4*)(pab + (size_t)yr*WW*2);
        const __half2* h = (const __half2*)&v;
        #pragma unroll
        for (int l=0;l<4;++l){
            float2 f = __half22float2(h[l]);
            sa[l]-=f.x; sb[l]-=f.y;
        }
    };
    const float inv = 1.0f/60.0f;
    for (int k=-29;k<=30;++k) accA(y0+k);
    auto emit = [&](int y){
        uint2 vd = *(const uint2*)(pd + (size_t)y*WW);
        const __half2* hd = (const __half2*)&vd;
        float2 f0 = __half22float2(hd[0]);
        float2 f1 = __half22float2(hd[1]);
        float4 o;
        o.x = (sa[0]*inv)*f0.x + sb[0]*inv;
        o.y = (sa[1]*inv)*f0.y + sb[1]*inv;
        o.z = (sa[2]*inv)*f1.x + sb[2]*inv;
        o.w = (sa[3]*inv)*f1.y + sb[3]*inv;
        *(float4*)(pq + (size_t)y*WW) = o;
    };
    emit(y0);
    for (int y=y0+1; y<y0+BT; ++y){
        accA(y+30);
        accS(y-30);
        emit(y);
    }
}

// ---------------------------------------------------------------- launch
extern "C" void kernel_launch(void* const* d_in, const int* in_sizes, int n_in,
                              void* d_out, int out_size, void* d_ws, size_t ws_size,
                              hipStream_t stream){
    const float* I = (const float*)d_in[0];
    float* qout = (float*)d_out;
    __half* ws = (__half*)d_ws;

    __half* p_dark = ws;                 // [0, NPXs)
    __half* p_eh   = ws + NPXs;          // [NPXs, 2N)
    __half* p_dim  = ws + 2*NPXs;        // [2N, 3N)
    __half* p_mp   = ws + 3*NPXs;        // [3N, 7N) packed 4 moments
    __half* p_ab   = ws;                 // aliases dark+eh (both dead before k_hab)

    k_dark_eh<<<NB*HH, 256, 0, stream>>>(I, p_dark, p_eh);
    k_erosv  <<<540,   256, 0, stream>>>(p_eh, p_dim);
    k_blurv4 <<<300,   256, 0, stream>>>(p_dim, p_dark, p_mp);
    k_hab    <<<NB*HH, 256, 0, stream>>>(p_mp, p_ab);
    k_final  <<<300,   256, 0, stream>>>(p_ab, p_dim, qout);
}